// Round 1
// baseline (24285.451 us; speedup 1.0000x reference)
//
#include <hip/hip_runtime.h>
#include <stdint.h>

// HardLSTM: T=2000 sequential steps, B=32, I=H=320, 4H=1280.
// Persistent cooperative kernel: 80 wgs x 256 thr, each wg owns 4 hidden units
// (16 gate rows). Fused [x_t | h] (K=640) per-step GEMM via bf16 hi/lo split
// MFMA (3 terms ~ fp32 accuracy). Global state: h packed (bf16hi<<16|bf16lo)
// double-buffered in d_ws. Hand-rolled device-scope barrier per step.

#define T_STEPS 2000
#define BATCH   32
#define IDIM    320
#define HDIM    320
#define KDIM    640
#define NWG     80
#define JPW     4              // hidden units per wg
#define RPW     16             // gate rows per wg = 4*JPW
#define LDK     644            // padded LDS K stride (bf16 elems)
#define NTH     256
#define HSZ     (BATCH*HDIM)   // 10240

typedef __attribute__((ext_vector_type(8))) short short8;
typedef __attribute__((ext_vector_type(4))) float f32x4;
typedef __attribute__((ext_vector_type(4))) unsigned short ushort4v;

__device__ __forceinline__ unsigned short f2bf(float f) {
    uint32_t u = __float_as_uint(f);
    u += 0x7FFFu + ((u >> 16) & 1u);          // RTNE
    return (unsigned short)(u >> 16);
}
__device__ __forceinline__ float bf2f(unsigned short s) {
    return __uint_as_float(((uint32_t)s) << 16);
}
__device__ __forceinline__ float sat01(float v)  { return fminf(fmaxf(v, 0.0f), 1.0f); }
__device__ __forceinline__ float clamp1(float v) { return fminf(fmaxf(v, -1.0f), 1.0f); }

// convert+stage one [32][320] fp32 tile into bf16 hi/lo LDS columns [0,320)
__device__ __forceinline__ void stage_x_tile(const float* __restrict__ xs,
                                             unsigned short* __restrict__ xhi,
                                             unsigned short* __restrict__ xlo,
                                             int tid) {
    const float4* x4 = (const float4*)xs;
    for (int idx = tid; idx < (BATCH * IDIM) / 4; idx += NTH) {
        float4 v = x4[idx];
        int b = idx / 80, k4 = (idx - b * 80) * 4;
        float e0 = v.x, e1 = v.y, e2 = v.z, e3 = v.w;
        ushort4v hi, lo;
        hi[0] = f2bf(e0); lo[0] = f2bf(e0 - bf2f(hi[0]));
        hi[1] = f2bf(e1); lo[1] = f2bf(e1 - bf2f(hi[1]));
        hi[2] = f2bf(e2); lo[2] = f2bf(e2 - bf2f(hi[2]));
        hi[3] = f2bf(e3); lo[3] = f2bf(e3 - bf2f(hi[3]));
        *(ushort4v*)(xhi + b * LDK + k4) = hi;
        *(ushort4v*)(xlo + b * LDK + k4) = lo;
    }
}

__global__ __launch_bounds__(NTH, 1)
void hard_lstm(const float* __restrict__ x, const float* __restrict__ w_ih,
               const float* __restrict__ w_hh, const float* __restrict__ b_ih,
               const float* __restrict__ b_hh, float* __restrict__ out,
               uint32_t* __restrict__ hbuf, uint32_t* __restrict__ bar)
{
    extern __shared__ char smem_raw[];
    unsigned short* whi = (unsigned short*)smem_raw;          // [RPW][LDK]
    unsigned short* wlo = whi + RPW * LDK;                    // [RPW][LDK]
    unsigned short* xhi = wlo + RPW * LDK;                    // [BATCH][LDK]
    unsigned short* xlo = xhi + BATCH * LDK;                  // [BATCH][LDK]
    float* red   = (float*)(xlo + BATCH * LDK);               // [2][16][17]
    float* biasS = red + 2 * 16 * 17;                         // [RPW]

    const int tid   = threadIdx.x;
    const int wg    = blockIdx.x;
    const int wave  = tid >> 6;
    const int lane  = tid & 63;
    const int row   = lane & 15;     // A row / B col within tile
    const int q     = lane >> 4;     // k-subblock (and output row quad)
    const int ntile = wave & 1;      // batch tile (0: b 0..15, 1: b 16..31)
    const int khalf = wave >> 1;     // K half (0: x, 1: h)
    const int j0    = wg * JPW;

    // ---- stage W slice into LDS (hi/lo), slice row r = j_local*4 + gate ----
    for (int idx = tid; idx < RPW * KDIM; idx += NTH) {
        int r = idx / KDIM, k = idx - r * KDIM;
        int g = r & 3, jl = r >> 2;
        int grow = g * HDIM + j0 + jl;
        float v = (k < IDIM) ? w_ih[grow * IDIM + k] : w_hh[grow * HDIM + (k - IDIM)];
        unsigned short hi = f2bf(v);
        whi[r * LDK + k] = hi;
        wlo[r * LDK + k] = f2bf(v - bf2f(hi));
    }
    if (tid < RPW) {
        int g = tid & 3, jl = tid >> 2;
        int grow = g * HDIM + j0 + jl;
        biasS[tid] = b_ih[grow] + b_hh[grow];
    }
    // zero this wg's slice of h state buffer 0
    for (int idx = tid; idx < BATCH * JPW; idx += NTH) {
        int b = idx >> 2, jl = idx & 3;
        hbuf[b * HDIM + j0 + jl] = 0u;
    }
    __syncthreads();

    // ---- hoist A (weight) fragments into registers for the whole run ----
    short8 ahi[10], alo[10];
    #pragma unroll
    for (int s = 0; s < 10; ++s) {
        int k = khalf * 320 + s * 32 + q * 8;
        ahi[s] = *(const short8*)(whi + row * LDK + k);
        alo[s] = *(const short8*)(wlo + row * LDK + k);
    }

    // ---- stage x[0] ----
    stage_x_tile(x, xhi, xlo, tid);

    float c_state = 0.0f;                 // valid on waves 0,1
    const int upd_b = ntile * 16 + row;   // batch owned in update phase
    const int upd_j = j0 + q;             // hidden unit owned in update phase

    #pragma unroll 1
    for (int t = 0; t < T_STEPS; ++t) {
        // ===== global barrier: h(t) ready in hbuf[t&1] =====
        __syncthreads();
        if (tid == 0) {
            unsigned target = (unsigned)(t + 1);
            unsigned prev = __hip_atomic_fetch_add(&bar[0], 1u, __ATOMIC_ACQ_REL,
                                                   __HIP_MEMORY_SCOPE_AGENT);
            if (prev == (unsigned)(NWG - 1)) {
                __hip_atomic_store(&bar[0], 0u, __ATOMIC_RELAXED, __HIP_MEMORY_SCOPE_AGENT);
                __hip_atomic_store(&bar[1], target, __ATOMIC_RELEASE, __HIP_MEMORY_SCOPE_AGENT);
            } else {
                while (__hip_atomic_load(&bar[1], __ATOMIC_RELAXED,
                                         __HIP_MEMORY_SCOPE_AGENT) < target) {}
                __builtin_amdgcn_fence(__ATOMIC_ACQUIRE, "agent");
            }
        }
        __syncthreads();

        // ===== stage h(t): unpack packed bf16 hi|lo into LDS cols [320,640) =====
        {
            const uint4* hs = (const uint4*)(hbuf + (t & 1) * HSZ);
            for (int idx = tid; idx < HSZ / 4; idx += NTH) {
                uint4 v = hs[idx];
                int b = idx / 80, k4 = IDIM + (idx - b * 80) * 4;
                ushort4v hi, lo;
                hi[0] = (unsigned short)(v.x >> 16); lo[0] = (unsigned short)v.x;
                hi[1] = (unsigned short)(v.y >> 16); lo[1] = (unsigned short)v.y;
                hi[2] = (unsigned short)(v.z >> 16); lo[2] = (unsigned short)v.z;
                hi[3] = (unsigned short)(v.w >> 16); lo[3] = (unsigned short)v.w;
                *(ushort4v*)(xhi + b * LDK + k4) = hi;
                *(ushort4v*)(xlo + b * LDK + k4) = lo;
            }
        }
        __syncthreads();

        // ===== MFMA: gates[16 rows][16 batch] per wave, K split across wave pairs =====
        f32x4 acc0 = {0.f, 0.f, 0.f, 0.f};
        f32x4 acc1 = {0.f, 0.f, 0.f, 0.f};
        f32x4 acc2 = {0.f, 0.f, 0.f, 0.f};
        {
            const unsigned short* bh_base = xhi + (ntile * 16 + row) * LDK + khalf * 320 + q * 8;
            const unsigned short* bl_base = xlo + (ntile * 16 + row) * LDK + khalf * 320 + q * 8;
            #pragma unroll
            for (int s = 0; s < 10; ++s) {
                short8 bh = *(const short8*)(bh_base + s * 32);
                short8 bl = *(const short8*)(bl_base + s * 32);
                acc0 = __builtin_amdgcn_mfma_f32_16x16x32_bf16(ahi[s], bh, acc0, 0, 0, 0);
                acc1 = __builtin_amdgcn_mfma_f32_16x16x32_bf16(alo[s], bh, acc1, 0, 0, 0);
                acc2 = __builtin_amdgcn_mfma_f32_16x16x32_bf16(ahi[s], bl, acc2, 0, 0, 0);
            }
        }
        f32x4 acc;
        #pragma unroll
        for (int v = 0; v < 4; ++v) acc[v] = acc0[v] + acc1[v] + acc2[v];

        if (wave >= 2) {
            #pragma unroll
            for (int v = 0; v < 4; ++v)
                red[(ntile * 16 + q * 4 + v) * 17 + row] = acc[v];
        }
        __syncthreads();

        // ===== gate math + state update (waves 0,1: lane owns (unit q, batch)) =====
        if (wave < 2) {
            float p[4];
            #pragma unroll
            for (int v = 0; v < 4; ++v)
                p[v] = acc[v] + red[(ntile * 16 + q * 4 + v) * 17 + row] + biasS[q * 4 + v];
            float gi = sat01(0.2f * p[0] + 0.5f);
            float gf = sat01(0.2f * p[1] + 0.5f);
            float gg = clamp1(p[2]);
            float go = sat01(0.2f * p[3] + 0.5f);
            c_state = gf * c_state + gi * gg;
            float h1 = go * clamp1(c_state);
            out[(size_t)t * HSZ + upd_b * HDIM + upd_j] = h1;
            unsigned short hhi = f2bf(h1);
            unsigned short hlo = f2bf(h1 - bf2f(hhi));
            hbuf[((t + 1) & 1) * HSZ + upd_b * HDIM + upd_j] = ((uint32_t)hhi << 16) | hlo;
        }

        // ===== prefetch/convert x[t+1] (x cols free after post-MFMA sync) =====
        if (t + 1 < T_STEPS)
            stage_x_tile(x + (size_t)(t + 1) * (BATCH * IDIM), xhi, xlo, tid);
    }
}

#define SMEM_BYTES (2*RPW*LDK*2 + 2*BATCH*LDK*2 + 2*16*17*4 + RPW*4)

extern "C" void kernel_launch(void* const* d_in, const int* in_sizes, int n_in,
                              void* d_out, int out_size, void* d_ws, size_t ws_size,
                              hipStream_t stream) {
    const float* x   = (const float*)d_in[0];
    const float* wih = (const float*)d_in[1];
    const float* whh = (const float*)d_in[2];
    const float* bih = (const float*)d_in[3];
    const float* bhh = (const float*)d_in[4];
    float* out = (float*)d_out;

    uint32_t* hbuf = (uint32_t*)d_ws;                              // 2*HSZ u32
    uint32_t* bar  = (uint32_t*)((char*)d_ws + (size_t)2 * HSZ * 4);

    hipMemsetAsync(bar, 0, 2 * sizeof(uint32_t), stream);

    hipFuncSetAttribute((const void*)hard_lstm,
                        hipFuncAttributeMaxDynamicSharedMemorySize, SMEM_BYTES);

    void* args[] = {(void*)&x, (void*)&wih, (void*)&whh, (void*)&bih, (void*)&bhh,
                    (void*)&out, (void*)&hbuf, (void*)&bar};
    hipError_t e = hipLaunchCooperativeKernel((const void*)hard_lstm, dim3(NWG), dim3(NTH),
                                              args, (unsigned)SMEM_BYTES, stream);
    if (e != hipSuccess) {
        // fallback: plain launch (80 blocks, 1/CU -> co-resident in practice)
        hipLaunchKernelGGL(hard_lstm, dim3(NWG), dim3(NTH), SMEM_BYTES, stream,
                           x, wih, whh, bih, bhh, out, hbuf, bar);
    }
}

// Round 2
// 22139.079 us; speedup vs baseline: 1.0969x; 1.0969x over previous
//
#include <hip/hip_runtime.h>
#include <stdint.h>

// HardLSTM: T=2000, B=32, I=H=320, 4H=1280.
// R2: two independent batch-groups (16 batches each, = MFMA N-width).
// Each group = 10 wgs x 512 thr; wg owns 32 hidden units (128 gate rows);
// each wave owns one 16-row tile with FULL K=640 in registers (bf16 hi/lo,
// 3-term MFMA ~ fp32). Sync = per-wg release flags (own cacheline) + parallel
// poll by 10 lanes of wave 0. h double-buffered packed bf16 hi|lo in d_ws.

#define T_STEPS 2000
#define BATCH   32
#define IDIM    320
#define HDIM    320
#define NWG     20
#define WPG     10             // wgs per group
#define NTH     512
#define GB      16             // batches per group
#define UPW     32             // hidden units per wg
#define LDK     644            // padded LDS K stride (bf16 elems)
#define HSZ     (BATCH*HDIM)   // 10240

typedef __attribute__((ext_vector_type(8))) short short8;
typedef __attribute__((ext_vector_type(4))) float f32x4;
typedef __attribute__((ext_vector_type(4))) unsigned short ushort4v;

static __device__ __forceinline__ unsigned short f2bf(float f) {
    uint32_t u = __float_as_uint(f);
    u += 0x7FFFu + ((u >> 16) & 1u);   // RTNE
    return (unsigned short)(u >> 16);
}
static __device__ __forceinline__ float bf2f(unsigned short s) {
    return __uint_as_float(((uint32_t)s) << 16);
}
static __device__ __forceinline__ float sat01(float v)  { return fminf(fmaxf(v, 0.f), 1.f); }
static __device__ __forceinline__ float clamp1(float v) { return fminf(fmaxf(v, -1.f), 1.f); }

static __device__ __forceinline__ void unpack_x(float4 v,
                                                unsigned short* hi_p,
                                                unsigned short* lo_p) {
    ushort4v hi, lo;
    hi[0] = f2bf(v.x); lo[0] = f2bf(v.x - bf2f(hi[0]));
    hi[1] = f2bf(v.y); lo[1] = f2bf(v.y - bf2f(hi[1]));
    hi[2] = f2bf(v.z); lo[2] = f2bf(v.z - bf2f(hi[2]));
    hi[3] = f2bf(v.w); lo[3] = f2bf(v.w - bf2f(hi[3]));
    *(ushort4v*)hi_p = hi;
    *(ushort4v*)lo_p = lo;
}
static __device__ __forceinline__ void unpack_h(uint4 v,
                                                unsigned short* hi_p,
                                                unsigned short* lo_p) {
    ushort4v hi, lo;
    hi[0] = (unsigned short)(v.x >> 16); lo[0] = (unsigned short)(v.x & 0xffffu);
    hi[1] = (unsigned short)(v.y >> 16); lo[1] = (unsigned short)(v.y & 0xffffu);
    hi[2] = (unsigned short)(v.z >> 16); lo[2] = (unsigned short)(v.z & 0xffffu);
    hi[3] = (unsigned short)(v.w >> 16); lo[3] = (unsigned short)(v.w & 0xffffu);
    *(ushort4v*)hi_p = hi;
    *(ushort4v*)lo_p = lo;
}

__global__ __launch_bounds__(NTH, 2)
void hard_lstm(const float* __restrict__ x, const float* __restrict__ w_ih,
               const float* __restrict__ w_hh, const float* __restrict__ b_ih,
               const float* __restrict__ b_hh, float* __restrict__ out,
               uint32_t* __restrict__ hbuf, uint32_t* __restrict__ flags)
{
    __shared__ unsigned short bhi_s[GB][LDK];   // [x | h] hi, per-group batch tile
    __shared__ unsigned short blo_s[GB][LDK];   // [x | h] lo

    const int tid  = threadIdx.x;
    const int wgg  = blockIdx.x;
    const int grp  = wgg / WPG;
    const int wgl  = wgg % WPG;
    const int wave = tid >> 6;
    const int lane = tid & 63;
    const int col  = lane & 15;    // MFMA row (A) / col (B)
    const int q    = lane >> 4;    // k-chunk / output row-quad

    // ---- A fragments (weights) -> registers, bf16 hi/lo, full K=640 ----
    short8 ahi[20], alo[20];
    {
        const int jA   = wgl * UPW + wave * 4 + (col >> 2);
        const int grow = (col & 3) * HDIM + jA;
        const float* wi = w_ih + (size_t)grow * IDIM;
        const float* wh = w_hh + (size_t)grow * HDIM;
        #pragma unroll
        for (int s = 0; s < 20; ++s) {
            #pragma unroll
            for (int jj = 0; jj < 8; ++jj) {
                int k = s * 32 + q * 8 + jj;
                float w = (k < IDIM) ? wi[k] : wh[k - IDIM];
                unsigned short hi = f2bf(w);
                ahi[s][jj] = (short)hi;
                alo[s][jj] = (short)f2bf(w - bf2f(hi));
            }
        }
    }

    const int jOut = wgl * UPW + wave * 4 + q;   // hidden unit owned by this lane
    const int bOut = grp * GB + col;             // batch owned by this lane
    float bias4[4];
    #pragma unroll
    for (int v = 0; v < 4; ++v)
        bias4[v] = b_ih[v * HDIM + jOut] + b_hh[v * HDIM + jOut];

    // ---- per-thread staging indices (16 batches x 320 elems = 1280 vec4) ----
    const int i0 = tid, i1 = tid + NTH, i2 = tid + 2 * NTH;
    const int b0 = i0 / 80, r0 = (i0 % 80) * 4;
    const int b1 = i1 / 80, r1 = (i1 % 80) * 4;
    const int b2 = i2 / 80, r2 = (i2 % 80) * 4;
    const bool has2 = (i2 < 1280);

    // ---- init: zero own slice of h slot 0, stage x(0) ----
    hbuf[(size_t)(grp * GB + (tid >> 5)) * HDIM + wgl * UPW + (tid & 31)] = 0u;
    {
        const float4* xs0 = (const float4*)(x + (size_t)(grp * GB) * IDIM);
        float4 v0 = xs0[i0], v1 = xs0[i1], v2 = {};
        if (has2) v2 = xs0[i2];
        unpack_x(v0, &bhi_s[b0][r0], &blo_s[b0][r0]);
        unpack_x(v1, &bhi_s[b1][r1], &blo_s[b1][r1]);
        if (has2) unpack_x(v2, &bhi_s[b2][r2], &blo_s[b2][r2]);
    }
    __syncthreads();
    if (tid == 0) {
        __builtin_amdgcn_fence(__ATOMIC_RELEASE, "agent");
        __hip_atomic_store(&flags[wgg * 16], 1u, __ATOMIC_RELAXED, __HIP_MEMORY_SCOPE_AGENT);
    }

    float c_state = 0.f;
    const int flag0 = grp * WPG;

    #pragma unroll 1
    for (int t = 0; t < T_STEPS; ++t) {
        // ===== wait: all 10 producer flags of this group >= t+1 =====
        if (wave == 0) {
            const uint32_t tgt = (uint32_t)(t + 1);
            const bool need = lane < WPG;
            const int fidx = (flag0 + (need ? lane : 0)) * 16;
            while (true) {
                uint32_t v = need ? __hip_atomic_load(&flags[fidx], __ATOMIC_RELAXED,
                                                      __HIP_MEMORY_SCOPE_AGENT)
                                  : tgt;
                if (__all((int)(v >= tgt))) break;
            }
            __builtin_amdgcn_fence(__ATOMIC_ACQUIRE, "agent");
        }
        __syncthreads();   // (B) flags seen + L2 invalidated

        // ===== stage h(t) -> LDS cols [320,640) =====
        {
            const uint4* hs = (const uint4*)(hbuf + (size_t)(t & 1) * HSZ
                                             + (size_t)(grp * GB) * HDIM);
            uint4 h0 = hs[i0], h1 = hs[i1], h2 = {};
            if (has2) h2 = hs[i2];
            unpack_h(h0, &bhi_s[b0][IDIM + r0], &blo_s[b0][IDIM + r0]);
            unpack_h(h1, &bhi_s[b1][IDIM + r1], &blo_s[b1][IDIM + r1]);
            if (has2) unpack_h(h2, &bhi_s[b2][IDIM + r2], &blo_s[b2][IDIM + r2]);
        }
        __syncthreads();   // (C) B-operand ready

        // ===== MFMA: 16 rows x 16 batches, K=640, 3-term hi/lo =====
        f32x4 acc0 = {0.f, 0.f, 0.f, 0.f};
        f32x4 acc1 = {0.f, 0.f, 0.f, 0.f};
        f32x4 acc2 = {0.f, 0.f, 0.f, 0.f};
        {
            const unsigned short* bh = &bhi_s[col][q * 8];
            const unsigned short* bl = &blo_s[col][q * 8];
            #pragma unroll
            for (int s = 0; s < 20; ++s) {
                short8 vbh = *(const short8*)(bh + s * 32);
                short8 vbl = *(const short8*)(bl + s * 32);
                acc0 = __builtin_amdgcn_mfma_f32_16x16x32_bf16(ahi[s], vbh, acc0, 0, 0, 0);
                acc1 = __builtin_amdgcn_mfma_f32_16x16x32_bf16(alo[s], vbh, acc1, 0, 0, 0);
                acc2 = __builtin_amdgcn_mfma_f32_16x16x32_bf16(ahi[s], vbl, acc2, 0, 0, 0);
            }
        }

        // ===== issue x(t+1) loads (hide behind gate math / store / flag) =====
        float4 xr0 = {}, xr1 = {}, xr2 = {};
        const bool havex = (t + 1 < T_STEPS);
        if (havex) {
            const float4* xs = (const float4*)(x + ((size_t)(t + 1) * BATCH + grp * GB) * IDIM);
            xr0 = xs[i0]; xr1 = xs[i1];
            if (has2) xr2 = xs[i2];
        }

        // ===== gate math: lane owns (batch bOut, unit jOut), gates v=0..3 =====
        float p[4];
        #pragma unroll
        for (int v = 0; v < 4; ++v) p[v] = acc0[v] + acc1[v] + acc2[v] + bias4[v];
        float gi = sat01(0.2f * p[0] + 0.5f);
        float gf = sat01(0.2f * p[1] + 0.5f);
        float gg = clamp1(p[2]);
        float go = sat01(0.2f * p[3] + 0.5f);
        c_state = gf * c_state + gi * gg;
        float h1 = go * clamp1(c_state);

        // h(t+1) packed hi|lo
        unsigned short hh = f2bf(h1);
        unsigned short hl = f2bf(h1 - bf2f(hh));
        hbuf[(size_t)((t + 1) & 1) * HSZ + (size_t)bOut * HDIM + jOut] =
            ((uint32_t)hh << 16) | (uint32_t)hl;

        __syncthreads();   // (A) all wg stores drained to L2 (vmcnt0), MFMA reads done
        if (tid == 0) {
            __builtin_amdgcn_fence(__ATOMIC_RELEASE, "agent");
            __hip_atomic_store(&flags[wgg * 16], (uint32_t)(t + 2), __ATOMIC_RELAXED,
                               __HIP_MEMORY_SCOPE_AGENT);
        }

        // out write (not consumed cross-wg; overlaps next poll)
        out[(size_t)t * HSZ + (size_t)bOut * HDIM + jOut] = h1;

        // x(t+1) -> LDS cols [0,320) (safe: all waves past (A))
        if (havex) {
            unpack_x(xr0, &bhi_s[b0][r0], &blo_s[b0][r0]);
            unpack_x(xr1, &bhi_s[b1][r1], &blo_s[b1][r1]);
            if (has2) unpack_x(xr2, &bhi_s[b2][r2], &blo_s[b2][r2]);
        }
    }
}

extern "C" void kernel_launch(void* const* d_in, const int* in_sizes, int n_in,
                              void* d_out, int out_size, void* d_ws, size_t ws_size,
                              hipStream_t stream) {
    const float* x   = (const float*)d_in[0];
    const float* wih = (const float*)d_in[1];
    const float* whh = (const float*)d_in[2];
    const float* bih = (const float*)d_in[3];
    const float* bhh = (const float*)d_in[4];
    float* out = (float*)d_out;

    uint32_t* hbuf  = (uint32_t*)d_ws;                               // 2*HSZ u32
    uint32_t* flags = (uint32_t*)((char*)d_ws + (size_t)2 * HSZ * 4); // 20 x 64B

    hipMemsetAsync(flags, 0, NWG * 16 * sizeof(uint32_t), stream);

    void* args[] = {(void*)&x, (void*)&wih, (void*)&whh, (void*)&bih, (void*)&bhh,
                    (void*)&out, (void*)&hbuf, (void*)&flags};
    hipError_t e = hipLaunchCooperativeKernel((const void*)hard_lstm, dim3(NWG), dim3(NTH),
                                              args, 0, stream);
    if (e != hipSuccess) {
        // 20 wgs always co-resident on 256 CUs
        hipLaunchKernelGGL(hard_lstm, dim3(NWG), dim3(NTH), 0, stream,
                           x, wih, whh, bih, bhh, out, hbuf, flags);
    }
}

// Round 3
// 9267.351 us; speedup vs baseline: 2.6205x; 2.3889x over previous
//
#include <hip/hip_runtime.h>
#include <stdint.h>

// HardLSTM R3: fence-free cross-wg protocol via L3-coherent (sc0 sc1) ops.
// 2 independent batch-groups x 10 wgs x 512thr; wave owns 16 gate-rows,
// full K=640 in registers (bf16 hi/lo). h state bf16-hi only, double-buffered
// in d_ws; per-wg flags (one 64B line per group). One __syncthreads per step.

#define T_STEPS 2000
#define BATCH   32
#define IDIM    320
#define HDIM    320
#define NWG     20
#define WPG     10
#define NTH     512
#define GB      16
#define UPW     32
#define LDK     328            // padded x-LDS stride (elems); 656B rows, 16B-aligned
#define HSLOT   (BATCH*HDIM)   // 10240 ushorts per h slot

typedef __attribute__((ext_vector_type(8))) short short8;
typedef __attribute__((ext_vector_type(4))) float f32x4;
typedef __attribute__((ext_vector_type(4))) unsigned short ushort4v;
typedef __attribute__((ext_vector_type(4))) unsigned int uint32x4;

static __device__ __forceinline__ unsigned short f2bf(float f) {
    uint32_t u = __float_as_uint(f);
    u += 0x7FFFu + ((u >> 16) & 1u);   // RTNE
    return (unsigned short)(u >> 16);
}
static __device__ __forceinline__ float bf2f(unsigned short s) {
    return __uint_as_float(((uint32_t)s) << 16);
}
static __device__ __forceinline__ float sat01(float v)  { return fminf(fmaxf(v, 0.f), 1.f); }
static __device__ __forceinline__ float clamp1(float v) { return fminf(fmaxf(v, -1.f), 1.f); }

static __device__ __forceinline__ void cvt_store(unsigned short* hi_p,
                                                 unsigned short* lo_p, float4 v) {
    ushort4v hi, lo;
    hi[0] = f2bf(v.x); lo[0] = f2bf(v.x - bf2f(hi[0]));
    hi[1] = f2bf(v.y); lo[1] = f2bf(v.y - bf2f(hi[1]));
    hi[2] = f2bf(v.z); lo[2] = f2bf(v.z - bf2f(hi[2]));
    hi[3] = f2bf(v.w); lo[3] = f2bf(v.w - bf2f(hi[3]));
    *(ushort4v*)hi_p = hi;
    *(ushort4v*)lo_p = lo;
}

__global__ __launch_bounds__(NTH, 2)
void hard_lstm(const float* __restrict__ x, const float* __restrict__ w_ih,
               const float* __restrict__ w_hh, const float* __restrict__ b_ih,
               const float* __restrict__ b_hh, float* __restrict__ out,
               unsigned short* __restrict__ hb, uint32_t* __restrict__ flags)
{
    __shared__ __align__(16) unsigned short xb[2][2][GB][LDK];  // [slot][hi/lo][b][k]
    __shared__ __align__(16) unsigned short h1s[2][GB][UPW];    // bf16 h1 scratch

    const int tid  = threadIdx.x;
    const int wgg  = blockIdx.x;
    const int grp  = wgg / WPG;
    const int wgl  = wgg % WPG;
    const int wave = tid >> 6;
    const int lane = tid & 63;
    const int col  = lane & 15;    // MFMA A-row / B-col (batch)
    const int q    = lane >> 4;    // k-chunk / output row-quad

    // ---- A fragments (weights) -> registers/AGPRs, bf16 hi/lo, K=640 ----
    short8 ahi[20], alo[20];
    {
        const int jA   = wgl * UPW + wave * 4 + (col >> 2);
        const int grow = (col & 3) * HDIM + jA;
        const float* wi = w_ih + (size_t)grow * IDIM;
        const float* wh = w_hh + (size_t)grow * HDIM;
        #pragma unroll
        for (int s = 0; s < 20; ++s) {
            #pragma unroll
            for (int jj = 0; jj < 8; ++jj) {
                int k = s * 32 + q * 8 + jj;
                float w = (k < IDIM) ? wi[k] : wh[k - IDIM];
                unsigned short hi = f2bf(w);
                ahi[s][jj] = (short)hi;
                alo[s][jj] = (short)f2bf(w - bf2f(hi));
            }
        }
    }

    const int jOut = wgl * UPW + wave * 4 + q;   // hidden unit owned by this lane
    const int bOut = grp * GB + col;             // batch owned by this lane
    float bias4[4];
    #pragma unroll
    for (int v = 0; v < 4; ++v)
        bias4[v] = b_ih[v * HDIM + jOut] + b_hh[v * HDIM + jOut];

    // staging indices (16 batches x 320 fp32 = 1280 float4)
    const int i0 = tid, i1 = tid + NTH, i2 = tid + 2 * NTH;
    const int sb0 = i0 / 80, sk0 = (i0 % 80) * 4;
    const int sb1 = i1 / 80, sk1 = (i1 % 80) * 4;
    const int sb2 = i2 / 80, sk2 = (i2 % 80) * 4;
    const bool has2 = (i2 < 1280);

    uint32_t* fline = flags + grp * 16;          // group's flag cacheline
    uint32_t* fpoll = &fline[lane % WPG];

    // h-fragment base (batch col, k-offset q*8), per slot
    const unsigned short* hp0 = hb + (size_t)bOut * HDIM + q * 8;

    // ---------- pre-loop (acts as step t=-1): h(0)=0, stage x(0), flag=1 ----------
    h1s[1][col][wave * 4 + q] = 0;
    {
        const float4* xs = (const float4*)(x + (size_t)(grp * GB) * IDIM);
        float4 v0 = xs[i0], v1 = xs[i1], v2 = {};
        if (has2) v2 = xs[i2];
        cvt_store(&xb[0][0][sb0][sk0], &xb[0][1][sb0][sk0], v0);
        cvt_store(&xb[0][0][sb1][sk1], &xb[0][1][sb1][sk1], v1);
        if (has2) cvt_store(&xb[0][0][sb2][sk2], &xb[0][1][sb2][sk2], v2);
    }
    __syncthreads();
    if (wave == 0) {
        const int b = lane >> 2, part = lane & 3;
        uint32x4 d = *(const uint32x4*)&h1s[1][b][part * 8];
        unsigned short* dst = hb + (size_t)(grp * GB + b) * HDIM + wgl * UPW + part * 8;
        asm volatile("global_store_dwordx4 %0, %1, off sc0 sc1\n\t"
                     "s_waitcnt vmcnt(0)" :: "v"(dst), "v"(d) : "memory");
        if (lane == 0)
            __hip_atomic_store(&fline[wgl], 1u, __ATOMIC_RELAXED, __HIP_MEMORY_SCOPE_SYSTEM);
    }

    float c_state = 0.f;

    #pragma unroll 1
    for (int t = 0; t < T_STEPS; ++t) {
        const int slot  = t & 1;
        const int slotn = slot ^ 1;

        // ---- x(t+1) prefetch (cached; consumed after gate math) ----
        float4 xr0 = {}, xr1 = {}, xr2 = {};
        const bool havex = (t + 1 < T_STEPS);
        if (havex) {
            const float4* xs = (const float4*)(x + ((size_t)(t + 1) * BATCH + grp * GB) * IDIM);
            xr0 = xs[i0]; xr1 = xs[i1];
            if (has2) xr2 = xs[i2];
        }

        // ---- poll: all 10 producer flags of this group >= t+1 (all waves) ----
        {
            const uint32_t tgt = (uint32_t)(t + 1);
            while (true) {
                uint32_t v = __hip_atomic_load(fpoll, __ATOMIC_RELAXED,
                                               __HIP_MEMORY_SCOPE_SYSTEM);
                if (__all((int)(v >= tgt))) break;
            }
        }

        // ---- h(t) B-fragments: 10x dwordx4, L3-coherent, single asm block ----
        uint32x4 hv[10];
        {
            const unsigned short* hp = hp0 + (size_t)slot * HSLOT;
            asm volatile(
                "global_load_dwordx4 %0, %10, off sc0 sc1\n\t"
                "global_load_dwordx4 %1, %10, off offset:64 sc0 sc1\n\t"
                "global_load_dwordx4 %2, %10, off offset:128 sc0 sc1\n\t"
                "global_load_dwordx4 %3, %10, off offset:192 sc0 sc1\n\t"
                "global_load_dwordx4 %4, %10, off offset:256 sc0 sc1\n\t"
                "global_load_dwordx4 %5, %10, off offset:320 sc0 sc1\n\t"
                "global_load_dwordx4 %6, %10, off offset:384 sc0 sc1\n\t"
                "global_load_dwordx4 %7, %10, off offset:448 sc0 sc1\n\t"
                "global_load_dwordx4 %8, %10, off offset:512 sc0 sc1\n\t"
                "global_load_dwordx4 %9, %10, off offset:576 sc0 sc1\n\t"
                "s_waitcnt vmcnt(0)"
                : "=&v"(hv[0]), "=&v"(hv[1]), "=&v"(hv[2]), "=&v"(hv[3]), "=&v"(hv[4]),
                  "=&v"(hv[5]), "=&v"(hv[6]), "=&v"(hv[7]), "=&v"(hv[8]), "=&v"(hv[9])
                : "v"(hp) : "memory");
        }

        // ---- MFMA: x-half 3-term (s=0..9), h-half 2-term (s=10..19) ----
        f32x4 acc0 = {0.f, 0.f, 0.f, 0.f};
        f32x4 acc1 = {0.f, 0.f, 0.f, 0.f};
        f32x4 acc2 = {0.f, 0.f, 0.f, 0.f};
        {
            const unsigned short* bxh = &xb[slot][0][col][q * 8];
            const unsigned short* bxl = &xb[slot][1][col][q * 8];
            #pragma unroll
            for (int s = 0; s < 10; ++s) {
                short8 bh = *(const short8*)(bxh + s * 32);
                short8 bl = *(const short8*)(bxl + s * 32);
                acc0 = __builtin_amdgcn_mfma_f32_16x16x32_bf16(ahi[s], bh, acc0, 0, 0, 0);
                acc1 = __builtin_amdgcn_mfma_f32_16x16x32_bf16(alo[s], bh, acc1, 0, 0, 0);
                acc2 = __builtin_amdgcn_mfma_f32_16x16x32_bf16(ahi[s], bl, acc2, 0, 0, 0);
            }
            #pragma unroll
            for (int s = 0; s < 10; ++s) {
                short8 bh = *(const short8*)&hv[s];
                acc0 = __builtin_amdgcn_mfma_f32_16x16x32_bf16(ahi[10 + s], bh, acc0, 0, 0, 0);
                acc1 = __builtin_amdgcn_mfma_f32_16x16x32_bf16(alo[10 + s], bh, acc1, 0, 0, 0);
            }
        }

        // ---- gate math: lane owns (bOut, jOut), all 4 gates ----
        float p[4];
        #pragma unroll
        for (int v = 0; v < 4; ++v) p[v] = acc0[v] + acc1[v] + acc2[v] + bias4[v];
        float gi = sat01(0.2f * p[0] + 0.5f);
        float gf = sat01(0.2f * p[1] + 0.5f);
        float gg = clamp1(p[2]);
        float go = sat01(0.2f * p[3] + 0.5f);
        c_state = gf * c_state + gi * gg;
        float h1 = go * clamp1(c_state);

        // h1 (bf16) -> LDS for wave0's coalesced publish
        h1s[slot][col][wave * 4 + q] = f2bf(h1);

        // x(t+1) -> LDS slotn
        if (havex) {
            cvt_store(&xb[slotn][0][sb0][sk0], &xb[slotn][1][sb0][sk0], xr0);
            cvt_store(&xb[slotn][0][sb1][sk1], &xb[slotn][1][sb1][sk1], xr1);
            if (has2) cvt_store(&xb[slotn][0][sb2][sk2], &xb[slotn][1][sb2][sk2], xr2);
        }

        // out (cached, not consumed cross-wg)
        out[(size_t)t * (BATCH * HDIM) + (size_t)bOut * HDIM + jOut] = h1;

        __syncthreads();

        // ---- publish h(t+1) + flag (wave0 only; wave-internal ordering) ----
        if (wave == 0) {
            const int b = lane >> 2, part = lane & 3;
            uint32x4 d = *(const uint32x4*)&h1s[slot][b][part * 8];
            unsigned short* dst = hb + (size_t)slotn * HSLOT
                                + (size_t)(grp * GB + b) * HDIM + wgl * UPW + part * 8;
            asm volatile("global_store_dwordx4 %0, %1, off sc0 sc1\n\t"
                         "s_waitcnt vmcnt(0)" :: "v"(dst), "v"(d) : "memory");
            if (lane == 0)
                __hip_atomic_store(&fline[wgl], (uint32_t)(t + 2), __ATOMIC_RELAXED,
                                   __HIP_MEMORY_SCOPE_SYSTEM);
        }
    }
}

extern "C" void kernel_launch(void* const* d_in, const int* in_sizes, int n_in,
                              void* d_out, int out_size, void* d_ws, size_t ws_size,
                              hipStream_t stream) {
    const float* x   = (const float*)d_in[0];
    const float* wih = (const float*)d_in[1];
    const float* whh = (const float*)d_in[2];
    const float* bih = (const float*)d_in[3];
    const float* bhh = (const float*)d_in[4];
    float* out = (float*)d_out;

    unsigned short* hb = (unsigned short*)d_ws;                      // 2*HSLOT ushorts = 40960 B
    uint32_t* flags = (uint32_t*)((char*)d_ws + (size_t)2 * HSLOT * 2);

    hipMemsetAsync(flags, 0, 2 * 16 * sizeof(uint32_t), stream);

    void* args[] = {(void*)&x, (void*)&wih, (void*)&whh, (void*)&bih, (void*)&bhh,
                    (void*)&out, (void*)&hb, (void*)&flags};
    hipError_t e = hipLaunchCooperativeKernel((const void*)hard_lstm, dim3(NWG), dim3(NTH),
                                              args, 0, stream);
    if (e != hipSuccess) {
        hipLaunchKernelGGL(hard_lstm, dim3(NWG), dim3(NTH), 0, stream,
                           x, wih, whh, bih, bhh, out, hb, flags);
    }
}